// Round 1
// baseline (1227.501 us; speedup 1.0000x reference)
//
#include <hip/hip_runtime.h>
#include <math.h>

#define D_  768
#define K_  17
#define B_  16
#define T_  4096
#define L_  1024
#define D3_ 2304

__device__ __forceinline__ float sigm(float x){ return 1.0f/(1.0f+__expf(-x)); }
__device__ __forceinline__ void ld4(const float* __restrict__ p, float* r){
  float4 v = *reinterpret_cast<const float4*>(p);
  r[0]=v.x; r[1]=v.y; r[2]=v.z; r[3]=v.w;
}
__device__ __forceinline__ void st4(float* __restrict__ p, const float* r){
  float4 v; v.x=r[0]; v.y=r[1]; v.z=r[2]; v.w=r[3];
  *reinterpret_cast<float4*>(p) = v;
}

__global__ void zero_kernel(float* __restrict__ p, int n){
  int i = blockIdx.x*256 + threadIdx.x;
  if(i<n) p[i] = 0.0f;
}

// ------------------- fused routing + aggregation -------------------
// route = sigmoid(H @ Wr^T + br)  (B,T,K);  agg = route^T @ H  (B,K,D)
// One pass over H. Thread owns d = {tid, tid+256, tid+512}; Wr and agg
// partials live in registers; 17 dots block-reduced per row.
#define SPB 32            // T-splits per batch
#define RPB (T_/SPB)      // 128 rows per block

__global__ __launch_bounds__(256) void route_agg_kernel(
    const float* __restrict__ H, const float* __restrict__ Wr,
    const float* __restrict__ br, float* __restrict__ agg)
{
  const int b     = blockIdx.x / SPB;
  const int chunk = blockIdx.x % SPB;
  const int tid   = threadIdx.x;
  const int lane  = tid & 63;
  const int wid   = tid >> 6;

  float wr0[K_], wr1[K_], wr2[K_];
#pragma unroll
  for(int k=0;k<K_;k++){
    wr0[k] = Wr[k*D_ + tid];
    wr1[k] = Wr[k*D_ + tid + 256];
    wr2[k] = Wr[k*D_ + tid + 512];
  }
  float a0[K_], a1[K_], a2[K_];
#pragma unroll
  for(int k=0;k<K_;k++){ a0[k]=0.f; a1[k]=0.f; a2[k]=0.f; }

  __shared__ float red[4*K_];
  __shared__ float wsm[K_];

  const float* Hb = H + ((size_t)b*T_ + (size_t)chunk*RPB)*D_;
  for(int r=0;r<RPB;r++){
    const float* hrow = Hb + (size_t)r*D_;
    float h0 = hrow[tid], h1 = hrow[tid+256], h2 = hrow[tid+512];
    float p[K_];
#pragma unroll
    for(int k=0;k<K_;k++)
      p[k] = h0*wr0[k] + h1*wr1[k] + h2*wr2[k];
#pragma unroll
    for(int k=0;k<K_;k++){
#pragma unroll
      for(int off=32; off>0; off>>=1) p[k] += __shfl_xor(p[k], off, 64);
    }
    if(lane == 0){
#pragma unroll
      for(int k=0;k<K_;k++) red[wid*K_+k] = p[k];
    }
    __syncthreads();
    if(tid < K_)
      wsm[tid] = sigm(red[tid] + red[K_+tid] + red[2*K_+tid] + red[3*K_+tid] + br[tid]);
    __syncthreads();
#pragma unroll
    for(int k=0;k<K_;k++){
      float w = wsm[k];
      a0[k] = fmaf(w,h0,a0[k]);
      a1[k] = fmaf(w,h1,a1[k]);
      a2[k] = fmaf(w,h2,a2[k]);
    }
    __syncthreads();   // protect red/wsm before next row overwrites
  }
  float* ab = agg + (size_t)b*K_*D_;
#pragma unroll
  for(int k=0;k<K_;k++){
    atomicAdd(&ab[k*D_ + tid      ], a0[k]);
    atomicAdd(&ab[k*D_ + tid + 256], a1[k]);
    atomicAdd(&ab[k*D_ + tid + 512], a2[k]);
  }
}

// ------------------- generic fp32 GEMM: C = A @ W^T (+bias) -------------------
// A: (M,Kd) row-major, W: (N,Kd) row-major, C: (M,N).
// 128x128 tile, BK=16, 256 threads, 8x8 per thread. blockIdx.z selects
// between two independent problems (same M,N,Kd) so small GEMMs co-run.
__global__ __launch_bounds__(256) void gemm_abt_dual(
    const float* __restrict__ A0, const float* __restrict__ W0,
    const float* __restrict__ bias0, float* __restrict__ C0,
    const float* __restrict__ A1, const float* __restrict__ W1,
    const float* __restrict__ bias1, float* __restrict__ C1,
    int M, int N, int Kd)
{
  __shared__ float As[16][132];
  __shared__ float Ws[16][132];

  const float* A; const float* W; const float* bias; float* C;
  if(blockIdx.z == 0){ A=A0; W=W0; bias=bias0; C=C0; }
  else               { A=A1; W=W1; bias=bias1; C=C1; }

  const int tid = threadIdx.x;
  const int tx  = tid & 15;
  const int ty  = tid >> 4;
  const int m0  = blockIdx.y * 128;
  const int n0  = blockIdx.x * 128;

  float acc[8][8];
#pragma unroll
  for(int i=0;i<8;i++)
#pragma unroll
    for(int j=0;j<8;j++) acc[i][j]=0.f;

  for(int kt=0; kt<Kd; kt+=16){
#pragma unroll
    for(int s=0;s<2;s++){
      int lin = s*256 + tid;       // 0..511 over (row, k-quad)
      int row = lin >> 2;
      int kq  = lin & 3;
      float4 av = make_float4(0.f,0.f,0.f,0.f);
      int gm = m0 + row;
      if(gm < M) av = *reinterpret_cast<const float4*>(&A[(size_t)gm*Kd + kt + kq*4]);
      As[kq*4+0][row]=av.x; As[kq*4+1][row]=av.y; As[kq*4+2][row]=av.z; As[kq*4+3][row]=av.w;
      float4 wv = make_float4(0.f,0.f,0.f,0.f);
      int gn = n0 + row;
      if(gn < N) wv = *reinterpret_cast<const float4*>(&W[(size_t)gn*Kd + kt + kq*4]);
      Ws[kq*4+0][row]=wv.x; Ws[kq*4+1][row]=wv.y; Ws[kq*4+2][row]=wv.z; Ws[kq*4+3][row]=wv.w;
    }
    __syncthreads();
#pragma unroll
    for(int kk=0;kk<16;kk++){
      float a_[8], b_[8];
      ld4(&As[kk][ty*4],    &a_[0]);
      ld4(&As[kk][ty*4+64], &a_[4]);
      ld4(&Ws[kk][tx*4],    &b_[0]);
      ld4(&Ws[kk][tx*4+64], &b_[4]);
#pragma unroll
      for(int i=0;i<8;i++)
#pragma unroll
        for(int j=0;j<8;j++) acc[i][j] = fmaf(a_[i], b_[j], acc[i][j]);
    }
    __syncthreads();
  }
#pragma unroll
  for(int i=0;i<8;i++){
    int gm = m0 + ty*4 + (i&3) + (i>>2)*64;
    if(gm >= M) continue;
#pragma unroll
    for(int jh=0;jh<2;jh++){
      int n = n0 + jh*64 + tx*4;
      float o[4];
#pragma unroll
      for(int c=0;c<4;c++){
        o[c] = acc[i][jh*4+c];
        if(bias) o[c] += bias[n+c];
      }
      st4(&C[(size_t)gm*N + n], o);
    }
  }
}

// ------------------- GRU gates + LayerNorm -> M_new -------------------
// one wave per (b,k) row; lane owns 12 consecutive d.
__global__ __launch_bounds__(256) void gru_ln_kernel(
    const float* __restrict__ gi, const float* __restrict__ gh,
    const float* __restrict__ Mo, const float* __restrict__ g_mem,
    const float* __restrict__ b_mem, float* __restrict__ Mn)
{
  int row  = blockIdx.x*4 + (threadIdx.x>>6);
  int lane = threadIdx.x & 63;
  if(row >= B_*K_) return;
  const float* gir = gi + (size_t)row*D3_;
  const float* ghr = gh + (size_t)row*D3_;
  const float* mo  = Mo + (size_t)row*D_;
  float h[12]; float s1=0.f, s2=0.f;
#pragma unroll
  for(int jj=0;jj<3;jj++){
    int d = lane*12 + jj*4;
    float xr[4], xz[4], xn[4], hr[4], hz[4], hn[4], mo4[4];
    ld4(gir + d, xr); ld4(gir + 768 + d, xz); ld4(gir + 1536 + d, xn);
    ld4(ghr + d, hr); ld4(ghr + 768 + d, hz); ld4(ghr + 1536 + d, hn);
    ld4(mo + d, mo4);
#pragma unroll
    for(int c=0;c<4;c++){
      float r  = sigm(xr[c]+hr[c]);
      float z  = sigm(xz[c]+hz[c]);
      float n  = tanhf(xn[c] + r*hn[c]);
      float hv = (1.f - z)*n + z*mo4[c];
      h[jj*4+c] = hv; s1 += hv; s2 += hv*hv;
    }
  }
#pragma unroll
  for(int off=32; off>0; off>>=1){ s1 += __shfl_xor(s1,off,64); s2 += __shfl_xor(s2,off,64); }
  float mean = s1*(1.f/768.f);
  float var  = s2*(1.f/768.f) - mean*mean;
  float rstd = rsqrtf(var + 1e-5f);
#pragma unroll
  for(int jj=0;jj<3;jj++){
    int d = lane*12 + jj*4;
    float g4[4], b4[4], o[4];
    ld4(g_mem + d, g4); ld4(b_mem + d, b4);
#pragma unroll
    for(int c=0;c<4;c++) o[c] = (h[jj*4+c]-mean)*rstd*g4[c] + b4[c];
    st4(Mn + (size_t)row*D_ + d, o);
  }
}

// ------------------- fused scores/softmax/ctx/LN/residual -------------------
// grid: 16 blocks per batch, 64 L-rows per block; K/V tiles in LDS (104 KB);
// each wave processes 2 rows per pass to amortize LDS reads.
__global__ __launch_bounds__(256) void attn_out_kernel(
    const float* __restrict__ Q, const float* __restrict__ Kt, const float* __restrict__ Vv,
    const float* __restrict__ dec, const float* __restrict__ g_attn, const float* __restrict__ b_attn,
    const float* __restrict__ m_gate, float* __restrict__ out)
{
  __shared__ float Ks[K_][D_];
  __shared__ float Vs[K_][D_];
  const int b   = blockIdx.x >> 4;
  const int lb  = blockIdx.x & 15;
  const int tid = threadIdx.x, lane = tid & 63, wid = tid >> 6;

  {
    const float4* Kg = reinterpret_cast<const float4*>(Kt + (size_t)b*K_*D_);
    const float4* Vg = reinterpret_cast<const float4*>(Vv + (size_t)b*K_*D_);
    float4* Ks4 = reinterpret_cast<float4*>(&Ks[0][0]);
    float4* Vs4 = reinterpret_cast<float4*>(&Vs[0][0]);
    for(int i=tid; i<K_*D_/4; i+=256){ Ks4[i]=Kg[i]; Vs4[i]=Vg[i]; }
  }
  float gv[12], bv[12];
#pragma unroll
  for(int jj=0;jj<3;jj++){ ld4(g_attn + lane*12 + jj*4, &gv[jj*4]); ld4(b_attn + lane*12 + jj*4, &bv[jj*4]); }
  const float mg = m_gate[0];
  __syncthreads();

  const float scale = 0.036084391824351615f; // 1/sqrt(768)
  for(int rp=0; rp<8; rp++){
    const int l0 = lb*64 + rp*8 + wid*2;   // rows l0, l0+1
    const size_t qb = ((size_t)b*L_ + l0)*D_ + lane*12;
    float q0[12], q1[12];
#pragma unroll
    for(int jj=0;jj<3;jj++){ ld4(Q + qb + jj*4, &q0[jj*4]); ld4(Q + qb + D_ + jj*4, &q1[jj*4]); }
    float s0[K_], s1[K_];
#pragma unroll
    for(int k=0;k<K_;k++){ s0[k]=0.f; s1[k]=0.f; }
#pragma unroll
    for(int k=0;k<K_;k++){
#pragma unroll
      for(int jj=0;jj<3;jj++){
        float kv[4]; ld4(&Ks[k][lane*12 + jj*4], kv);
#pragma unroll
        for(int c=0;c<4;c++){
          s0[k] = fmaf(q0[jj*4+c], kv[c], s0[k]);
          s1[k] = fmaf(q1[jj*4+c], kv[c], s1[k]);
        }
      }
    }
#pragma unroll
    for(int k=0;k<K_;k++){
#pragma unroll
      for(int off=32; off>0; off>>=1){
        s0[k] += __shfl_xor(s0[k], off, 64);
        s1[k] += __shfl_xor(s1[k], off, 64);
      }
    }
    float mx0 = s0[0], mx1 = s1[0];
#pragma unroll
    for(int k=1;k<K_;k++){ mx0 = fmaxf(mx0, s0[k]); mx1 = fmaxf(mx1, s1[k]); }
    float sum0=0.f, sum1=0.f;
#pragma unroll
    for(int k=0;k<K_;k++){
      s0[k] = __expf((s0[k]-mx0)*scale); sum0 += s0[k];
      s1[k] = __expf((s1[k]-mx1)*scale); sum1 += s1[k];
    }
    const float inv0 = 1.f/sum0, inv1 = 1.f/sum1;
    float c0[12], c1[12];
#pragma unroll
    for(int j=0;j<12;j++){ c0[j]=0.f; c1[j]=0.f; }
#pragma unroll
    for(int k=0;k<K_;k++){
#pragma unroll
      for(int jj=0;jj<3;jj++){
        float vx[4]; ld4(&Vs[k][lane*12 + jj*4], vx);
#pragma unroll
        for(int c=0;c<4;c++){
          c0[jj*4+c] = fmaf(s0[k], vx[c], c0[jj*4+c]);
          c1[jj*4+c] = fmaf(s1[k], vx[c], c1[jj*4+c]);
        }
      }
    }
    float a1=0.f,a2=0.f,b1=0.f,b2=0.f;
#pragma unroll
    for(int j=0;j<12;j++){
      c0[j]*=inv0; c1[j]*=inv1;
      a1+=c0[j]; a2+=c0[j]*c0[j]; b1+=c1[j]; b2+=c1[j]*c1[j];
    }
#pragma unroll
    for(int off=32; off>0; off>>=1){
      a1 += __shfl_xor(a1,off,64); a2 += __shfl_xor(a2,off,64);
      b1 += __shfl_xor(b1,off,64); b2 += __shfl_xor(b2,off,64);
    }
    const float mean0 = a1*(1.f/768.f), mean1 = b1*(1.f/768.f);
    const float rstd0 = rsqrtf(a2*(1.f/768.f)-mean0*mean0 + 1e-5f);
    const float rstd1 = rsqrtf(b2*(1.f/768.f)-mean1*mean1 + 1e-5f);
#pragma unroll
    for(int jj=0;jj<3;jj++){
      float d0[4], d1[4], o0[4], o1[4];
      ld4(dec + qb + jj*4, d0); ld4(dec + qb + D_ + jj*4, d1);
#pragma unroll
      for(int c=0;c<4;c++){
        o0[c] = d0[c] + mg*((c0[jj*4+c]-mean0)*rstd0*gv[jj*4+c] + bv[jj*4+c]);
        o1[c] = d1[c] + mg*((c1[jj*4+c]-mean1)*rstd1*gv[jj*4+c] + bv[jj*4+c]);
      }
      st4(out + qb + jj*4, o0); st4(out + qb + D_ + jj*4, o1);
    }
  }
}

// ------------------- launcher -------------------
extern "C" void kernel_launch(void* const* d_in, const int* in_sizes, int n_in,
                              void* d_out, int out_size, void* d_ws, size_t ws_size,
                              hipStream_t stream)
{
  const float* H      = (const float*)d_in[0];
  const float* M_old  = (const float*)d_in[1];
  const float* dec    = (const float*)d_in[2];
  const float* Wr     = (const float*)d_in[3];
  const float* br     = (const float*)d_in[4];
  const float* W_ih   = (const float*)d_in[5];
  const float* W_hh   = (const float*)d_in[6];
  const float* b_ih   = (const float*)d_in[7];
  const float* b_hh   = (const float*)d_in[8];
  const float* g_mem  = (const float*)d_in[9];
  const float* b_mem  = (const float*)d_in[10];
  const float* Wq     = (const float*)d_in[11];
  const float* Wk     = (const float*)d_in[12];
  const float* Wv     = (const float*)d_in[13];
  const float* g_attn = (const float*)d_in[14];
  const float* b_attn = (const float*)d_in[15];
  const float* m_gate = (const float*)d_in[16];
  float* out = (float*)d_out;
  float* ws  = (float*)d_ws;

  // workspace layout (floats): 14,671,872 total (= 58.7 MB)
  float* agg  = ws;                  // 16*17*768   = 208896
  float* gi   = agg  + 208896;       // 16*17*2304  = 626688
  float* gh   = gi   + 626688;
  float* Mnew = gh   + 626688;       // 208896
  float* Ktb  = Mnew + 208896;       // 208896
  float* Vb   = Ktb  + 208896;       // 208896
  float* Qb   = Vb   + 208896;       // 16*1024*768 = 12582912

  zero_kernel<<<816, 256, 0, stream>>>(agg, 208896);

  route_agg_kernel<<<B_*SPB, 256, 0, stream>>>(H, Wr, br, agg);

  // gi = agg @ W_ih^T + b_ih ; gh = M_old @ W_hh^T + b_hh   (272 x 2304, K=768)
  gemm_abt_dual<<<dim3(D3_/128, (B_*K_+127)/128, 2), 256, 0, stream>>>(
      agg, W_ih, b_ih, gi,  M_old, W_hh, b_hh, gh,  B_*K_, D3_, D_);

  gru_ln_kernel<<<(B_*K_)/4, 256, 0, stream>>>(gi, gh, M_old, g_mem, b_mem, Mnew);

  // Kt = M_new @ Wk^T ; V = M_new @ Wv^T   (272 x 768, K=768)
  gemm_abt_dual<<<dim3(D_/128, (B_*K_+127)/128, 2), 256, 0, stream>>>(
      Mnew, Wk, nullptr, Ktb,  Mnew, Wv, nullptr, Vb,  B_*K_, D_, D_);

  // Q = dec @ Wq^T   (16384 x 768, K=768)  — the big one
  gemm_abt_dual<<<dim3(D_/128, (B_*L_)/128, 1), 256, 0, stream>>>(
      dec, Wq, nullptr, Qb,  dec, Wq, nullptr, Qb,  B_*L_, D_, D_);

  attn_out_kernel<<<B_*(L_/64), 256, 0, stream>>>(
      Qb, Ktb, Vb, dec, g_attn, b_attn, m_gate, out);
}

// Round 3
// 702.363 us; speedup vs baseline: 1.7477x; 1.7477x over previous
//
#include <hip/hip_runtime.h>
#include <math.h>

#define D_  768
#define K_  17
#define B_  16
#define T_  4096
#define L_  1024
#define D3_ 2304
#define NROWS (B_*T_)   // 65536
#define AGG_RPB 128     // rows per agg block
#define AGG_NB  (NROWS/AGG_RPB)        // 512 partial blocks
#define AGG_PPB (T_/AGG_RPB)           // 32 partials per batch

__device__ __forceinline__ float sigm(float x){ return 1.0f/(1.0f+__expf(-x)); }
__device__ __forceinline__ void ld4(const float* __restrict__ p, float* r){
  float4 v = *reinterpret_cast<const float4*>(p);
  r[0]=v.x; r[1]=v.y; r[2]=v.z; r[3]=v.w;
}
__device__ __forceinline__ void st4(float* __restrict__ p, const float* r){
  float4 v; v.x=r[0]; v.y=r[1]; v.z=r[2]; v.w=r[3];
  *reinterpret_cast<float4*>(p) = v;
}

// ------------------- pass 1: route = sigmoid(H @ Wr^T + br) -------------------
// 512 threads (8 waves); wave = 16 row-slots x 4 col-quarters (192 cols each).
// Serial dots from registers+LDS — zero barriers in hot loop, 2-step butterfly.
// Wr in LDS quarter-major [q][k][196]: q-stride 3332 ≡ 4 (mod 32) banks ->
// the 4 q-groups read disjoint bank-quads (conflict-free broadcast x16).
__global__ __launch_bounds__(512) void route_kernel(
    const float* __restrict__ H, const float* __restrict__ Wr,
    const float* __restrict__ br, float* __restrict__ route)
{
  __shared__ float Wrs[4*K_*196];
  const int tid = threadIdx.x;
  for(int i = tid; i < K_*192; i += 512){
    int k = i / 192, c4 = i % 192;
    int q = c4 / 48, cc = (c4 % 48)*4;
    float4 v = *reinterpret_cast<const float4*>(&Wr[k*D_ + c4*4]);
    float* dst = &Wrs[(q*K_ + k)*196 + cc];
    dst[0]=v.x; dst[1]=v.y; dst[2]=v.z; dst[3]=v.w;
  }
  __syncthreads();

  const int lane = tid & 63, wid = tid >> 6;
  const int q = lane & 3, rs = lane >> 2;
  const int row = blockIdx.x*128 + wid*16 + rs;
  const float* hrow = H + (size_t)row*D_ + q*192;
  const int qbase = q*K_*196;

  float s[K_];
#pragma unroll
  for(int k=0;k<K_;k++) s[k]=0.f;

#pragma unroll 4
  for(int cq=0; cq<48; cq++){
    float4 h4 = *reinterpret_cast<const float4*>(hrow + cq*4);
#pragma unroll
    for(int k=0;k<K_;k++){
      float4 w4 = *reinterpret_cast<const float4*>(&Wrs[qbase + k*196 + cq*4]);
      s[k] = fmaf(h4.x,w4.x, fmaf(h4.y,w4.y, fmaf(h4.z,w4.z, fmaf(h4.w,w4.w, s[k]))));
    }
  }
#pragma unroll
  for(int k=0;k<K_;k++){
    s[k] += __shfl_xor(s[k], 1, 64);
    s[k] += __shfl_xor(s[k], 2, 64);
  }
  float* rrow = route + (size_t)row*K_;
#pragma unroll
  for(int j=0;j<4;j++){
    int k = q*4 + j;
    rrow[k] = sigm(s[k] + br[k]);
  }
  if(q==0) rrow[16] = sigm(s[16] + br[16]);
}

// ------------------- pass 2a: per-block partial of agg = route^T @ H -------------------
// thread owns d in {tid, tid+256, tid+512}; register accumulators; route chunk
// staged in LDS (broadcast reads); partial written per block (no atomics).
__global__ __launch_bounds__(256) void agg_partial_kernel(
    const float* __restrict__ H, const float* __restrict__ route,
    float* __restrict__ partial)
{
  __shared__ float rs[AGG_RPB*K_];   // 2176 floats
  const int tid = threadIdx.x;
  const int row0 = blockIdx.x*AGG_RPB;
  for(int i = tid; i < AGG_RPB*K_/4; i += 256){   // 544 float4s, ALL covered
    float4 v = *reinterpret_cast<const float4*>(&route[(size_t)row0*K_ + i*4]);
    rs[i*4+0]=v.x; rs[i*4+1]=v.y; rs[i*4+2]=v.z; rs[i*4+3]=v.w;
  }
  __syncthreads();

  float a0[K_], a1[K_], a2[K_];
#pragma unroll
  for(int k=0;k<K_;k++){ a0[k]=0.f; a1[k]=0.f; a2[k]=0.f; }

  const float* Hb = H + (size_t)row0*D_;
  for(int r=0;r<AGG_RPB;r++){
    float h0 = Hb[(size_t)r*D_ + tid];
    float h1 = Hb[(size_t)r*D_ + tid + 256];
    float h2 = Hb[(size_t)r*D_ + tid + 512];
    const float* w = &rs[r*K_];
#pragma unroll
    for(int k=0;k<K_;k++){
      float wv = w[k];
      a0[k] = fmaf(wv,h0,a0[k]);
      a1[k] = fmaf(wv,h1,a1[k]);
      a2[k] = fmaf(wv,h2,a2[k]);
    }
  }
  float* pb = partial + (size_t)blockIdx.x*K_*D_;
#pragma unroll
  for(int k=0;k<K_;k++){
    pb[k*D_ + tid      ] = a0[k];
    pb[k*D_ + tid + 256] = a1[k];
    pb[k*D_ + tid + 512] = a2[k];
  }
}

// ------------------- pass 2b: reduce partials -> agg (B,K,D) -------------------
__global__ __launch_bounds__(256) void agg_reduce_kernel(
    const float* __restrict__ partial, float* __restrict__ agg)
{
  int idx = blockIdx.x*256 + threadIdx.x;          // over B_*K_*D_ = 208896
  int b = idx / (K_*D_);
  int i = idx % (K_*D_);
  const float* p = partial + ((size_t)b*AGG_PPB)*(K_*D_) + i;
  float s = 0.f;
#pragma unroll
  for(int j=0;j<AGG_PPB;j++) s += p[(size_t)j*(K_*D_)];
  agg[idx] = s;
}

// ------------------- 64x64-tile fp32 GEMM (dual-problem) -------------------
// BTRANS=false: C = A @ W^T (+bias), W is (N,Kd) row-major.
// BTRANS=true : C = A @ W     (+bias), W is (Kd,N) row-major.
template<bool BTRANS>
__global__ __launch_bounds__(256) void gemm64(
    const float* __restrict__ A0, const float* __restrict__ W0,
    const float* __restrict__ bias0, float* __restrict__ C0,
    const float* __restrict__ A1, const float* __restrict__ W1,
    const float* __restrict__ bias1, float* __restrict__ C1,
    int M, int N, int Kd)
{
  __shared__ float As[32][68];
  __shared__ float Ws[32][68];
  const float* A; const float* W; const float* bias; float* C;
  if(blockIdx.z == 0){ A=A0; W=W0; bias=bias0; C=C0; }
  else               { A=A1; W=W1; bias=bias1; C=C1; }

  const int tid = threadIdx.x;
  const int tx = tid & 15, ty = tid >> 4;
  const int n0 = blockIdx.x*64, m0 = blockIdx.y*64;

  float acc[4][4];
#pragma unroll
  for(int i=0;i<4;i++)
#pragma unroll
    for(int j=0;j<4;j++) acc[i][j]=0.f;

  for(int kt=0; kt<Kd; kt+=32){
#pragma unroll
    for(int s=0;s<2;s++){
      int lin = s*256 + tid;
      { // A tile: 64 rows x 32 k, store k-major
        int row = lin >> 3, kq = lin & 7;
        float4 v = make_float4(0.f,0.f,0.f,0.f);
        if(m0+row < M) v = *reinterpret_cast<const float4*>(&A[(size_t)(m0+row)*Kd + kt + kq*4]);
        As[kq*4+0][row]=v.x; As[kq*4+1][row]=v.y; As[kq*4+2][row]=v.z; As[kq*4+3][row]=v.w;
      }
      if(!BTRANS){
        int row = lin >> 3, kq = lin & 7;
        float4 v = make_float4(0.f,0.f,0.f,0.f);
        if(n0+row < N) v = *reinterpret_cast<const float4*>(&W[(size_t)(n0+row)*Kd + kt + kq*4]);
        Ws[kq*4+0][row]=v.x; Ws[kq*4+1][row]=v.y; Ws[kq*4+2][row]=v.z; Ws[kq*4+3][row]=v.w;
      } else {
        int kr = lin >> 4, cq = lin & 15;
        float4 v = *reinterpret_cast<const float4*>(&W[(size_t)(kt+kr)*N + n0 + cq*4]);
        *reinterpret_cast<float4*>(&Ws[kr][cq*4]) = v;
      }
    }
    __syncthreads();
#pragma unroll
    for(int kk=0;kk<32;kk++){
      float a_[4], b_[4];
      ld4(&As[kk][ty*4], a_);
      ld4(&Ws[kk][tx*4], b_);
#pragma unroll
      for(int i=0;i<4;i++)
#pragma unroll
        for(int j=0;j<4;j++) acc[i][j] = fmaf(a_[i], b_[j], acc[i][j]);
    }
    __syncthreads();
  }
#pragma unroll
  for(int i=0;i<4;i++){
    int gm = m0 + ty*4 + i;
    if(gm >= M) continue;
    int n = n0 + tx*4;
    float o[4];
#pragma unroll
    for(int c=0;c<4;c++){
      o[c] = acc[i][c];
      if(bias) o[c] += bias[n+c];
    }
    st4(&C[(size_t)gm*N + n], o);
  }
}

// ------------------- GRU gates + LayerNorm -> M_new -------------------
__global__ __launch_bounds__(256) void gru_ln_kernel(
    const float* __restrict__ gi, const float* __restrict__ gh,
    const float* __restrict__ Mo, const float* __restrict__ g_mem,
    const float* __restrict__ b_mem, float* __restrict__ Mn)
{
  int row  = blockIdx.x*4 + (threadIdx.x>>6);
  int lane = threadIdx.x & 63;
  if(row >= B_*K_) return;
  const float* gir = gi + (size_t)row*D3_;
  const float* ghr = gh + (size_t)row*D3_;
  const float* mo  = Mo + (size_t)row*D_;
  float h[12]; float s1=0.f, s2=0.f;
#pragma unroll
  for(int jj=0;jj<3;jj++){
    int d = lane*12 + jj*4;
    float xr[4], xz[4], xn[4], hr[4], hz[4], hn[4], mo4[4];
    ld4(gir + d, xr); ld4(gir + 768 + d, xz); ld4(gir + 1536 + d, xn);
    ld4(ghr + d, hr); ld4(ghr + 768 + d, hz); ld4(ghr + 1536 + d, hn);
    ld4(mo + d, mo4);
#pragma unroll
    for(int c=0;c<4;c++){
      float r  = sigm(xr[c]+hr[c]);
      float z  = sigm(xz[c]+hz[c]);
      float n  = tanhf(xn[c] + r*hn[c]);
      float hv = (1.f - z)*n + z*mo4[c];
      h[jj*4+c] = hv; s1 += hv; s2 += hv*hv;
    }
  }
#pragma unroll
  for(int off=32; off>0; off>>=1){ s1 += __shfl_xor(s1,off,64); s2 += __shfl_xor(s2,off,64); }
  float mean = s1*(1.f/768.f);
  float var  = s2*(1.f/768.f) - mean*mean;
  float rstd = rsqrtf(var + 1e-5f);
#pragma unroll
  for(int jj=0;jj<3;jj++){
    int d = lane*12 + jj*4;
    float g4[4], b4[4], o[4];
    ld4(g_mem + d, g4); ld4(b_mem + d, b4);
#pragma unroll
    for(int c=0;c<4;c++) o[c] = (h[jj*4+c]-mean)*rstd*g4[c] + b4[c];
    st4(Mn + (size_t)row*D_ + d, o);
  }
}

// ------------------- fused scores/softmax/ctx/LN/residual -------------------
// scores[l,k] = dec[l] . KK2[k]  (Q eliminated: KK2 = Kt @ Wq). dec row is
// read once and reused for the residual.
__global__ __launch_bounds__(256) void attn_out_kernel(
    const float* __restrict__ KK2, const float* __restrict__ Vv,
    const float* __restrict__ dec, const float* __restrict__ g_attn,
    const float* __restrict__ b_attn, const float* __restrict__ m_gate,
    float* __restrict__ out)
{
  __shared__ float Ks[K_][D_];
  __shared__ float Vs[K_][D_];
  const int b   = blockIdx.x >> 4;
  const int lb  = blockIdx.x & 15;
  const int tid = threadIdx.x, lane = tid & 63, wid = tid >> 6;

  {
    const float4* Kg = reinterpret_cast<const float4*>(KK2 + (size_t)b*K_*D_);
    const float4* Vg = reinterpret_cast<const float4*>(Vv  + (size_t)b*K_*D_);
    float4* Ks4 = reinterpret_cast<float4*>(&Ks[0][0]);
    float4* Vs4 = reinterpret_cast<float4*>(&Vs[0][0]);
    for(int i=tid; i<K_*D_/4; i+=256){ Ks4[i]=Kg[i]; Vs4[i]=Vg[i]; }
  }
  float gv[12], bv[12];
#pragma unroll
  for(int jj=0;jj<3;jj++){ ld4(g_attn + lane*12 + jj*4, &gv[jj*4]); ld4(b_attn + lane*12 + jj*4, &bv[jj*4]); }
  const float mg = m_gate[0];
  __syncthreads();

  const float scale = 0.036084391824351615f; // 1/sqrt(768)
  for(int rp=0; rp<8; rp++){
    const int l0 = lb*64 + rp*8 + wid*2;   // rows l0, l0+1
    const size_t qb = ((size_t)b*L_ + l0)*D_ + lane*12;
    float d0[12], d1[12];
#pragma unroll
    for(int jj=0;jj<3;jj++){ ld4(dec + qb + jj*4, &d0[jj*4]); ld4(dec + qb + D_ + jj*4, &d1[jj*4]); }
    float s0[K_], s1[K_];
#pragma unroll
    for(int k=0;k<K_;k++){ s0[k]=0.f; s1[k]=0.f; }
#pragma unroll
    for(int k=0;k<K_;k++){
#pragma unroll
      for(int jj=0;jj<3;jj++){
        float kv[4]; ld4(&Ks[k][lane*12 + jj*4], kv);
#pragma unroll
        for(int c=0;c<4;c++){
          s0[k] = fmaf(d0[jj*4+c], kv[c], s0[k]);
          s1[k] = fmaf(d1[jj*4+c], kv[c], s1[k]);
        }
      }
    }
#pragma unroll
    for(int k=0;k<K_;k++){
#pragma unroll
      for(int off=32; off>0; off>>=1){
        s0[k] += __shfl_xor(s0[k], off, 64);
        s1[k] += __shfl_xor(s1[k], off, 64);
      }
    }
    float mx0 = s0[0], mx1 = s1[0];
#pragma unroll
    for(int k=1;k<K_;k++){ mx0 = fmaxf(mx0, s0[k]); mx1 = fmaxf(mx1, s1[k]); }
    float sum0=0.f, sum1=0.f;
#pragma unroll
    for(int k=0;k<K_;k++){
      s0[k] = __expf((s0[k]-mx0)*scale); sum0 += s0[k];
      s1[k] = __expf((s1[k]-mx1)*scale); sum1 += s1[k];
    }
    const float inv0 = 1.f/sum0, inv1 = 1.f/sum1;
    float c0[12], c1[12];
#pragma unroll
    for(int j=0;j<12;j++){ c0[j]=0.f; c1[j]=0.f; }
#pragma unroll
    for(int k=0;k<K_;k++){
#pragma unroll
      for(int jj=0;jj<3;jj++){
        float vx[4]; ld4(&Vs[k][lane*12 + jj*4], vx);
#pragma unroll
        for(int c=0;c<4;c++){
          c0[jj*4+c] = fmaf(s0[k], vx[c], c0[jj*4+c]);
          c1[jj*4+c] = fmaf(s1[k], vx[c], c1[jj*4+c]);
        }
      }
    }
    float a1=0.f,a2=0.f,b1=0.f,b2=0.f;
#pragma unroll
    for(int j=0;j<12;j++){
      c0[j]*=inv0; c1[j]*=inv1;
      a1+=c0[j]; a2+=c0[j]*c0[j]; b1+=c1[j]; b2+=c1[j]*c1[j];
    }
#pragma unroll
    for(int off=32; off>0; off>>=1){
      a1 += __shfl_xor(a1,off,64); a2 += __shfl_xor(a2,off,64);
      b1 += __shfl_xor(b1,off,64); b2 += __shfl_xor(b2,off,64);
    }
    const float mean0 = a1*(1.f/768.f), mean1 = b1*(1.f/768.f);
    const float rstd0 = rsqrtf(a2*(1.f/768.f)-mean0*mean0 + 1e-5f);
    const float rstd1 = rsqrtf(b2*(1.f/768.f)-mean1*mean1 + 1e-5f);
#pragma unroll
    for(int jj=0;jj<3;jj++){
      float o0[4], o1[4];
#pragma unroll
      for(int c=0;c<4;c++){
        o0[c] = d0[jj*4+c] + mg*((c0[jj*4+c]-mean0)*rstd0*gv[jj*4+c] + bv[jj*4+c]);
        o1[c] = d1[jj*4+c] + mg*((c1[jj*4+c]-mean1)*rstd1*gv[jj*4+c] + bv[jj*4+c]);
      }
      st4(out + qb + jj*4, o0); st4(out + qb + D_ + jj*4, o1);
    }
  }
}

// ------------------- launcher -------------------
extern "C" void kernel_launch(void* const* d_in, const int* in_sizes, int n_in,
                              void* d_out, int out_size, void* d_ws, size_t ws_size,
                              hipStream_t stream)
{
  const float* H      = (const float*)d_in[0];
  const float* M_old  = (const float*)d_in[1];
  const float* dec    = (const float*)d_in[2];
  const float* Wr     = (const float*)d_in[3];
  const float* br     = (const float*)d_in[4];
  const float* W_ih   = (const float*)d_in[5];
  const float* W_hh   = (const float*)d_in[6];
  const float* b_ih   = (const float*)d_in[7];
  const float* b_hh   = (const float*)d_in[8];
  const float* g_mem  = (const float*)d_in[9];
  const float* b_mem  = (const float*)d_in[10];
  const float* Wq     = (const float*)d_in[11];
  const float* Wk     = (const float*)d_in[12];
  const float* Wv     = (const float*)d_in[13];
  const float* g_attn = (const float*)d_in[14];
  const float* b_attn = (const float*)d_in[15];
  const float* m_gate = (const float*)d_in[16];
  float* out = (float*)d_out;
  float* ws  = (float*)d_ws;

  // workspace (floats):
  // route 1,114,112 | partial 512*13,056=6,684,672 | agg 208,896 |
  // gi/gh 626,688x2 | Mnew/Kt/V/KK2 208,896x4  => 10,096,640 (40.4 MB)
  float* route   = ws;
  float* partial = route   + (size_t)NROWS*K_;
  float* agg     = partial + (size_t)AGG_NB*K_*D_;
  float* gi      = agg     + 208896;
  float* gh      = gi      + 626688;
  float* Mnew    = gh      + 626688;
  float* Ktb     = Mnew    + 208896;
  float* Vb      = Ktb     + 208896;
  float* KK2b    = Vb      + 208896;

  route_kernel<<<NROWS/128, 512, 0, stream>>>(H, Wr, br, route);

  agg_partial_kernel<<<AGG_NB, 256, 0, stream>>>(H, route, partial);
  agg_reduce_kernel<<<(B_*K_*D_)/256, 256, 0, stream>>>(partial, agg);

  // gi = agg @ W_ih^T + b_ih ; gh = M_old @ W_hh^T + b_hh   (272 x 2304, K=768)
  gemm64<false><<<dim3(D3_/64, 5, 2), 256, 0, stream>>>(
      agg, W_ih, b_ih, gi,  M_old, W_hh, b_hh, gh,  B_*K_, D3_, D_);

  gru_ln_kernel<<<(B_*K_)/4, 256, 0, stream>>>(gi, gh, M_old, g_mem, b_mem, Mnew);

  // Kt = M_new @ Wk^T ; V = M_new @ Wv^T   (272 x 768, K=768)
  gemm64<false><<<dim3(D_/64, 5, 2), 256, 0, stream>>>(
      Mnew, Wk, nullptr, Ktb,  Mnew, Wv, nullptr, Vb,  B_*K_, D_, D_);

  // KK2 = Kt @ Wq   (272 x 768, K=768) — replaces the 19.3 GF Q projection
  gemm64<true><<<dim3(D_/64, 5, 1), 256, 0, stream>>>(
      Ktb, Wq, nullptr, KK2b,  Ktb, Wq, nullptr, KK2b,  B_*K_, D_, D_);

  attn_out_kernel<<<B_*(L_/64), 256, 0, stream>>>(
      KK2b, Vb, dec, g_attn, b_attn, m_gate, out);
}